// Round 3
// baseline (458.925 us; speedup 1.0000x reference)
//
#include <hip/hip_runtime.h>
#include <hip/hip_bf16.h>

// B=2, C=8, L=1024, H=512
// out[((b*1024+l)*1024+m)*8 + c] = a[b,c,l] + bb[b,c,m] + sum_h start*v4*end
//
// Single fused kernel. WG tile = 64(l) x 64(m) x all 8 c-planes, K=512 in 16
// steps of BK=32. Wave w computes the full 64x64 for planes {2w, 2w+1}.
// a/bb row-dots accumulate during staging. Epilogue transposes the 128 KB
// output tile through LDS in two 64 KB halves so every global store
// instruction writes 1 KB of contiguous, line-aligned data (R2 showed
// 8B-stride-32B stores cause 13x write amplification via L2 RMW).

typedef short bf16x8 __attribute__((ext_vector_type(8)));
typedef float f32x4 __attribute__((ext_vector_type(4)));

__device__ __forceinline__ unsigned pk2(float x, float y) {
    union { __hip_bfloat162 h; unsigned u; } cv;
    cv.h = __float22bfloat162_rn(make_float2(x, y));
    return cv.u;
}

// K-loop LDS layout with row-pair XOR swizzle (no padding; 2-way = free).
__device__ __forceinline__ int lds_off(int plane, int row, int j) {
    const int rp = row >> 1;
    const int pc = (j + ((row & 1) << 2)) ^ (rp & 7);
    return plane * 2048 + rp * 64 + pc * 8;
}

__global__ __launch_bounds__(256, 2) void fused_k(const float* __restrict__ sh,
                                                  const float* __restrict__ eh,
                                                  const float* __restrict__ v,
                                                  float* __restrict__ out) {
    __shared__ __align__(16) unsigned char smem[65536];
    unsigned short* As = (unsigned short*)smem;      // 8*2048 ushort = 32 KB
    unsigned short* Bs = As + 8 * 2048;              // 32 KB

    const int t   = threadIdx.x;
    const int bid = blockIdx.x;
    // XCD swizzle: all 16 mt-blocks of a (b,lt) strip land on one XCD.
    const int xcd  = bid & 7, slot = bid >> 3;
    const int b    = xcd >> 2;
    const int lt   = (xcd & 3) * 4 + (slot >> 4);
    const int mt   = slot & 15;

    const int lane = t & 63, wave = t >> 6;
    const int ln15 = lane & 15, quad = lane >> 4;

    const int rowt = t >> 2;   // staging row 0..63
    const int jt   = t & 3;    // staging k-chunk

    const float* baseA = sh + (size_t)b * 8 * 524288 + ((size_t)lt * 64 + rowt) * 512;
    const float* baseB = eh + (size_t)b * 8 * 524288 + ((size_t)mt * 64 + rowt) * 512;

    f32x4 acc[2][4][4] = {};
    float sa[8] = {0,0,0,0,0,0,0,0};
    float sb[8] = {0,0,0,0,0,0,0,0};

    for (int ks = 0; ks < 16; ++ks) {
        const int k0 = ks * 32 + jt * 8;

        float4 w1a = *(const float4*)(v + k0);          float4 w1b = *(const float4*)(v + k0 + 4);
        float4 w2a = *(const float4*)(v + 512 + k0);    float4 w2b = *(const float4*)(v + 512 + k0 + 4);
        float4 w3a = *(const float4*)(v + 1024 + k0);   float4 w3b = *(const float4*)(v + 1024 + k0 + 4);
        float4 w4a = *(const float4*)(v + 1536 + k0);   float4 w4b = *(const float4*)(v + 1536 + k0 + 4);
        const float4 wAa = make_float4(w1a.x + w3a.x, w1a.y + w3a.y, w1a.z + w3a.z, w1a.w + w3a.w);
        const float4 wAb = make_float4(w1b.x + w3b.x, w1b.y + w3b.y, w1b.z + w3b.z, w1b.w + w3b.w);
        const float4 wBa = make_float4(w2a.x - w3a.x, w2a.y - w3a.y, w2a.z - w3a.z, w2a.w - w3a.w);
        const float4 wBb = make_float4(w2b.x - w3b.x, w2b.y - w3b.y, w2b.z - w3b.z, w2b.w - w3b.w);

        float4 av[8][2], bv[8][2];
        #pragma unroll
        for (int p = 0; p < 8; ++p) {
            const float* pa = baseA + (size_t)p * 524288 + k0;
            const float* pb = baseB + (size_t)p * 524288 + k0;
            av[p][0] = *(const float4*)pa;  av[p][1] = *(const float4*)(pa + 4);
            bv[p][0] = *(const float4*)pb;  bv[p][1] = *(const float4*)(pb + 4);
        }

        __syncthreads();   // previous iteration's fragment reads complete

        #pragma unroll
        for (int p = 0; p < 8; ++p) {
            float4 a0 = av[p][0], a1 = av[p][1];
            float4 b0 = bv[p][0], b1 = bv[p][1];
            sa[p] += a0.x*wAa.x + a0.y*wAa.y + a0.z*wAa.z + a0.w*wAa.w
                   + a1.x*wAb.x + a1.y*wAb.y + a1.z*wAb.z + a1.w*wAb.w;
            sb[p] += b0.x*wBa.x + b0.y*wBa.y + b0.z*wBa.z + b0.w*wBa.w
                   + b1.x*wBb.x + b1.y*wBb.y + b1.z*wBb.z + b1.w*wBb.w;
            a0.x *= w4a.x; a0.y *= w4a.y; a0.z *= w4a.z; a0.w *= w4a.w;
            a1.x *= w4b.x; a1.y *= w4b.y; a1.z *= w4b.z; a1.w *= w4b.w;
            uint4 pa, pb2;
            pa.x  = pk2(a0.x, a0.y); pa.y  = pk2(a0.z, a0.w);
            pa.z  = pk2(a1.x, a1.y); pa.w  = pk2(a1.z, a1.w);
            pb2.x = pk2(b0.x, b0.y); pb2.y = pk2(b0.z, b0.w);
            pb2.z = pk2(b1.x, b1.y); pb2.w = pk2(b1.z, b1.w);
            *(uint4*)&As[lds_off(p, rowt, jt)] = pa;
            *(uint4*)&Bs[lds_off(p, rowt, jt)] = pb2;
        }

        __syncthreads();

        bf16x8 aF[2][4], bF[2][4];
        #pragma unroll
        for (int c2 = 0; c2 < 2; ++c2) {
            const int c = wave * 2 + c2;
            #pragma unroll
            for (int i = 0; i < 4; ++i) {
                aF[c2][i] = *(const bf16x8*)&As[lds_off(c, i * 16 + ln15, quad)];
                bF[c2][i] = *(const bf16x8*)&Bs[lds_off(c, i * 16 + ln15, quad)];
            }
        }
        #pragma unroll
        for (int c2 = 0; c2 < 2; ++c2)
            #pragma unroll
            for (int i = 0; i < 4; ++i)
                #pragma unroll
                for (int j = 0; j < 4; ++j)
                    acc[c2][i][j] = __builtin_amdgcn_mfma_f32_16x16x32_bf16(
                        aF[c2][i], bF[c2][j], acc[c2][i][j], 0, 0, 0);
    }

    // ---- reduce a/bb partials across the 4 k-chunk threads ----
    #pragma unroll
    for (int p = 0; p < 8; ++p) {
        sa[p] += __shfl_xor(sa[p], 1, 64); sa[p] += __shfl_xor(sa[p], 2, 64);
        sb[p] += __shfl_xor(sb[p], 1, 64); sb[p] += __shfl_xor(sb[p], 2, 64);
    }
    __syncthreads();                     // all fragment reads done; reuse smem
    float* aS = (float*)smem;            // a[plane][row]  : 512 floats
    float* bS = aS + 512;                // bb[plane][row] : 512 floats
    if (jt == 0) {
        #pragma unroll
        for (int p = 0; p < 8; ++p) {
            aS[p * 64 + rowt] = sa[p];
            bS[p * 64 + rowt] = sb[p];
        }
    }
    __syncthreads();

    // ---- fold a + bb into acc (registers) ----
    {
        float avv[2][4][4], bvv[2][4];
        #pragma unroll
        for (int c2 = 0; c2 < 2; ++c2) {
            const int c = wave * 2 + c2;
            #pragma unroll
            for (int i = 0; i < 4; ++i)
                #pragma unroll
                for (int r = 0; r < 4; ++r)
                    avv[c2][i][r] = aS[c * 64 + i * 16 + quad * 4 + r];
            #pragma unroll
            for (int j = 0; j < 4; ++j)
                bvv[c2][j] = bS[c * 64 + j * 16 + ln15];
        }
        #pragma unroll
        for (int c2 = 0; c2 < 2; ++c2)
            #pragma unroll
            for (int i = 0; i < 4; ++i)
                #pragma unroll
                for (int j = 0; j < 4; ++j)
                    #pragma unroll
                    for (int r = 0; r < 4; ++r)
                        acc[c2][i][j][r] += avv[c2][i][r] + bvv[c2][j];
    }
    __syncthreads();   // sums buffer consumed; smem free for transpose

    // ---- epilogue: LDS transpose per 32-row half, fully coalesced stores ----
    float2* T = (float2*)smem;   // [wave][i2*16 + j*4 + r][lane] float2 = 64 KB
    const int chalf = t & 1;
    #pragma unroll
    for (int half = 0; half < 2; ++half) {
        #pragma unroll
        for (int i2 = 0; i2 < 2; ++i2)
            #pragma unroll
            for (int j = 0; j < 4; ++j)
                #pragma unroll
                for (int r = 0; r < 4; ++r)
                    T[wave * 2048 + (i2 * 16 + j * 4 + r) * 64 + lane] =
                        make_float2(acc[0][half * 2 + i2][j][r],
                                    acc[1][half * 2 + i2][j][r]);
        __syncthreads();
        #pragma unroll
        for (int iter = 0; iter < 16; ++iter) {
            const int slotp = iter * 128 + (t >> 1);      // 0..2047
            const int llp = slotp >> 6, mm = slotp & 63;  // half-local l, m
            const int i2 = llp >> 4, q2 = (llp >> 2) & 3, r = llp & 3;
            const int j = mm >> 4, ln = mm & 15;
            const int lidx = (i2 * 16 + j * 4 + r) * 64 + q2 * 16 + ln;
            const float2 lo = T[(chalf * 2 + 0) * 2048 + lidx];
            const float2 hi = T[(chalf * 2 + 1) * 2048 + lidx];
            const int l = lt * 64 + half * 32 + llp;
            const int m = mt * 64 + mm;
            *(float4*)&out[((size_t)(b * 1024 + l) * 1024 + m) * 8 + chalf * 4] =
                make_float4(lo.x, lo.y, hi.x, hi.y);
        }
        if (half == 0) __syncthreads();
    }
}

extern "C" void kernel_launch(void* const* d_in, const int* in_sizes, int n_in,
                              void* d_out, int out_size, void* d_ws, size_t ws_size,
                              hipStream_t stream) {
    const float* sh = (const float*)d_in[0];
    const float* eh = (const float*)d_in[1];
    const float* v  = (const float*)d_in[2];
    float* out = (float*)d_out;
    (void)d_ws; (void)ws_size; (void)in_sizes; (void)n_in; (void)out_size;

    fused_k<<<512, 256, 0, stream>>>(sh, eh, v, out);
}

// Round 4
// 250.931 us; speedup vs baseline: 1.8289x; 1.8289x over previous
//
#include <hip/hip_runtime.h>
#include <hip/hip_bf16.h>

// B=2, C=8, L=1024, H=512
// out[((b*1024+l)*1024+m)*8 + c] = a[b,c,l] + bb[b,c,m] + sum_h start*v4*end
//
// Single fused kernel. WG tile = 64(l) x 64(m) x all 8 c-planes, K=512 in 16
// steps of BK=32. Wave w computes the full 64x64 for planes {2w, 2w+1}.
// a/bb row-dots accumulate during staging. Epilogue transposes the output
// tile through LDS so every global store writes full 128B lines.
//
// R4: staging register-double-buffered in 4 groups of 2 planes (max 64 VGPRs
// of loads in flight). R2/R3's 850+ MB WRITE_SIZE was scratch spill traffic
// from 128 float4 staging regs colliding with the 128-AGPR accumulator under
// the 256-reg unified budget — NOT store coalescing.

typedef short bf16x8 __attribute__((ext_vector_type(8)));
typedef float f32x4 __attribute__((ext_vector_type(4)));

__device__ __forceinline__ unsigned pk2(float x, float y) {
    union { __hip_bfloat162 h; unsigned u; } cv;
    cv.h = __float22bfloat162_rn(make_float2(x, y));
    return cv.u;
}

// K-loop LDS layout with row-pair XOR swizzle (no padding; 2-way = free).
__device__ __forceinline__ int lds_off(int plane, int row, int j) {
    const int rp = row >> 1;
    const int pc = (j + ((row & 1) << 2)) ^ (rp & 7);
    return plane * 2048 + rp * 64 + pc * 8;
}

__global__ __launch_bounds__(256, 2) void fused_k(const float* __restrict__ sh,
                                                  const float* __restrict__ eh,
                                                  const float* __restrict__ v,
                                                  float* __restrict__ out) {
    __shared__ __align__(16) unsigned char smem[65536];
    unsigned short* As = (unsigned short*)smem;      // 8*2048 ushort = 32 KB
    unsigned short* Bs = As + 8 * 2048;              // 32 KB

    const int t   = threadIdx.x;
    const int bid = blockIdx.x;
    // XCD swizzle: all 16 mt-blocks of a (b,lt) strip land on one XCD.
    const int xcd  = bid & 7, slot = bid >> 3;
    const int b    = xcd >> 2;
    const int lt   = (xcd & 3) * 4 + (slot >> 4);
    const int mt   = slot & 15;

    const int lane = t & 63, wave = t >> 6;
    const int ln15 = lane & 15, quad = lane >> 4;

    const int rowt = t >> 2;   // staging row 0..63
    const int jt   = t & 3;    // staging k-chunk

    const float* baseA = sh + (size_t)b * 8 * 524288 + ((size_t)lt * 64 + rowt) * 512;
    const float* baseB = eh + (size_t)b * 8 * 524288 + ((size_t)mt * 64 + rowt) * 512;

    f32x4 acc[2][4][4] = {};
    float sa[8] = {0,0,0,0,0,0,0,0};
    float sb[8] = {0,0,0,0,0,0,0,0};

    for (int ks = 0; ks < 16; ++ks) {
        const int k0 = ks * 32 + jt * 8;

        float4 w1a = *(const float4*)(v + k0);          float4 w1b = *(const float4*)(v + k0 + 4);
        float4 w2a = *(const float4*)(v + 512 + k0);    float4 w2b = *(const float4*)(v + 512 + k0 + 4);
        float4 w3a = *(const float4*)(v + 1024 + k0);   float4 w3b = *(const float4*)(v + 1024 + k0 + 4);
        float4 w4a = *(const float4*)(v + 1536 + k0);   float4 w4b = *(const float4*)(v + 1536 + k0 + 4);
        const float4 wAa = make_float4(w1a.x + w3a.x, w1a.y + w3a.y, w1a.z + w3a.z, w1a.w + w3a.w);
        const float4 wAb = make_float4(w1b.x + w3b.x, w1b.y + w3b.y, w1b.z + w3b.z, w1b.w + w3b.w);
        const float4 wBa = make_float4(w2a.x - w3a.x, w2a.y - w3a.y, w2a.z - w3a.z, w2a.w - w3a.w);
        const float4 wBb = make_float4(w2b.x - w3b.x, w2b.y - w3b.y, w2b.z - w3b.z, w2b.w - w3b.w);

        // register double-buffer: 2 plane-pair groups in flight (64 VGPRs max)
        float4 ga[2][2][2], gb[2][2][2];   // [buf][plane-in-pair][half]
        #pragma unroll
        for (int pp = 0; pp < 2; ++pp) {
            const float* pa = baseA + (size_t)pp * 524288 + k0;
            const float* pb = baseB + (size_t)pp * 524288 + k0;
            ga[0][pp][0] = *(const float4*)pa;  ga[0][pp][1] = *(const float4*)(pa + 4);
            gb[0][pp][0] = *(const float4*)pb;  gb[0][pp][1] = *(const float4*)(pb + 4);
        }

        __syncthreads();   // previous iteration's fragment reads complete

        #pragma unroll
        for (int g = 0; g < 4; ++g) {
            const int cur = g & 1, nxt = cur ^ 1;
            if (g < 3) {
                #pragma unroll
                for (int pp = 0; pp < 2; ++pp) {
                    const int p = (g + 1) * 2 + pp;
                    const float* pa = baseA + (size_t)p * 524288 + k0;
                    const float* pb = baseB + (size_t)p * 524288 + k0;
                    ga[nxt][pp][0] = *(const float4*)pa;  ga[nxt][pp][1] = *(const float4*)(pa + 4);
                    gb[nxt][pp][0] = *(const float4*)pb;  gb[nxt][pp][1] = *(const float4*)(pb + 4);
                }
            }
            #pragma unroll
            for (int pp = 0; pp < 2; ++pp) {
                const int p = g * 2 + pp;
                float4 a0 = ga[cur][pp][0], a1 = ga[cur][pp][1];
                float4 b0 = gb[cur][pp][0], b1 = gb[cur][pp][1];
                sa[p] += a0.x*wAa.x + a0.y*wAa.y + a0.z*wAa.z + a0.w*wAa.w
                       + a1.x*wAb.x + a1.y*wAb.y + a1.z*wAb.z + a1.w*wAb.w;
                sb[p] += b0.x*wBa.x + b0.y*wBa.y + b0.z*wBa.z + b0.w*wBa.w
                       + b1.x*wBb.x + b1.y*wBb.y + b1.z*wBb.z + b1.w*wBb.w;
                a0.x *= w4a.x; a0.y *= w4a.y; a0.z *= w4a.z; a0.w *= w4a.w;
                a1.x *= w4b.x; a1.y *= w4b.y; a1.z *= w4b.z; a1.w *= w4b.w;
                uint4 pa4, pb4;
                pa4.x = pk2(a0.x, a0.y); pa4.y = pk2(a0.z, a0.w);
                pa4.z = pk2(a1.x, a1.y); pa4.w = pk2(a1.z, a1.w);
                pb4.x = pk2(b0.x, b0.y); pb4.y = pk2(b0.z, b0.w);
                pb4.z = pk2(b1.x, b1.y); pb4.w = pk2(b1.z, b1.w);
                *(uint4*)&As[lds_off(p, rowt, jt)] = pa4;
                *(uint4*)&Bs[lds_off(p, rowt, jt)] = pb4;
            }
        }

        __syncthreads();

        bf16x8 aF[2][4], bF[2][4];
        #pragma unroll
        for (int c2 = 0; c2 < 2; ++c2) {
            const int c = wave * 2 + c2;
            #pragma unroll
            for (int i = 0; i < 4; ++i) {
                aF[c2][i] = *(const bf16x8*)&As[lds_off(c, i * 16 + ln15, quad)];
                bF[c2][i] = *(const bf16x8*)&Bs[lds_off(c, i * 16 + ln15, quad)];
            }
        }
        #pragma unroll
        for (int c2 = 0; c2 < 2; ++c2)
            #pragma unroll
            for (int i = 0; i < 4; ++i)
                #pragma unroll
                for (int j = 0; j < 4; ++j)
                    acc[c2][i][j] = __builtin_amdgcn_mfma_f32_16x16x32_bf16(
                        aF[c2][i], bF[c2][j], acc[c2][i][j], 0, 0, 0);
    }

    // ---- reduce a/bb partials across the 4 k-chunk threads ----
    #pragma unroll
    for (int p = 0; p < 8; ++p) {
        sa[p] += __shfl_xor(sa[p], 1, 64); sa[p] += __shfl_xor(sa[p], 2, 64);
        sb[p] += __shfl_xor(sb[p], 1, 64); sb[p] += __shfl_xor(sb[p], 2, 64);
    }
    __syncthreads();                     // all fragment reads done; reuse smem
    float* aS = (float*)smem;            // a[plane][row]  : 512 floats
    float* bS = aS + 512;                // bb[plane][row] : 512 floats
    if (jt == 0) {
        #pragma unroll
        for (int p = 0; p < 8; ++p) {
            aS[p * 64 + rowt] = sa[p];
            bS[p * 64 + rowt] = sb[p];
        }
    }
    __syncthreads();

    // ---- fold a + bb into acc (registers) ----
    {
        float avv[2][4][4], bvv[2][4];
        #pragma unroll
        for (int c2 = 0; c2 < 2; ++c2) {
            const int c = wave * 2 + c2;
            #pragma unroll
            for (int i = 0; i < 4; ++i)
                #pragma unroll
                for (int r = 0; r < 4; ++r)
                    avv[c2][i][r] = aS[c * 64 + i * 16 + quad * 4 + r];
            #pragma unroll
            for (int j = 0; j < 4; ++j)
                bvv[c2][j] = bS[c * 64 + j * 16 + ln15];
        }
        #pragma unroll
        for (int c2 = 0; c2 < 2; ++c2)
            #pragma unroll
            for (int i = 0; i < 4; ++i)
                #pragma unroll
                for (int j = 0; j < 4; ++j)
                    #pragma unroll
                    for (int r = 0; r < 4; ++r)
                        acc[c2][i][j][r] += avv[c2][i][r] + bvv[c2][j];
    }
    __syncthreads();   // sums buffer consumed; smem free for transpose

    // ---- epilogue: LDS transpose per 32-row half, fully coalesced stores ----
    float2* T = (float2*)smem;   // [wave][i2*16 + j*4 + r][lane] float2 = 64 KB
    const int chalf = t & 1;
    #pragma unroll
    for (int half = 0; half < 2; ++half) {
        #pragma unroll
        for (int i2 = 0; i2 < 2; ++i2)
            #pragma unroll
            for (int j = 0; j < 4; ++j)
                #pragma unroll
                for (int r = 0; r < 4; ++r)
                    T[wave * 2048 + (i2 * 16 + j * 4 + r) * 64 + lane] =
                        make_float2(acc[0][half * 2 + i2][j][r],
                                    acc[1][half * 2 + i2][j][r]);
        __syncthreads();
        #pragma unroll
        for (int iter = 0; iter < 16; ++iter) {
            const int slotp = iter * 128 + (t >> 1);      // 0..2047
            const int llp = slotp >> 6, mm = slotp & 63;  // half-local l, m
            const int i2 = llp >> 4, q2 = (llp >> 2) & 3, r = llp & 3;
            const int j = mm >> 4, ln = mm & 15;
            const int lidx = (i2 * 16 + j * 4 + r) * 64 + q2 * 16 + ln;
            const float2 lo = T[(chalf * 2 + 0) * 2048 + lidx];
            const float2 hi = T[(chalf * 2 + 1) * 2048 + lidx];
            const int l = lt * 64 + half * 32 + llp;
            const int m = mt * 64 + mm;
            *(float4*)&out[((size_t)(b * 1024 + l) * 1024 + m) * 8 + chalf * 4] =
                make_float4(lo.x, lo.y, hi.x, hi.y);
        }
        if (half == 0) __syncthreads();
    }
}

extern "C" void kernel_launch(void* const* d_in, const int* in_sizes, int n_in,
                              void* d_out, int out_size, void* d_ws, size_t ws_size,
                              hipStream_t stream) {
    const float* sh = (const float*)d_in[0];
    const float* eh = (const float*)d_in[1];
    const float* v  = (const float*)d_in[2];
    float* out = (float*)d_out;
    (void)d_ws; (void)ws_size; (void)in_sizes; (void)n_in; (void)out_size;

    fused_k<<<512, 256, 0, stream>>>(sh, eh, v, out);
}